// Round 5
// baseline (81.006 us; speedup 1.0000x reference)
//
#include <hip/hip_runtime.h>
#include <math.h>

#define SIZE 512
#define NPTS 128
#define HALF 64   // segments per thread (2 threads cooperate per pixel)

__global__ __launch_bounds__(256) void contour_mask_kernel(
    const float* __restrict__ contour, float* __restrict__ out)
{
    __shared__ float2 c[NPTS];
    __shared__ float partial[128];

    const int tid = threadIdx.x;
    if (tid < NPTS) {
        // contour is (128, 2) row-major: [x0, y0, x1, y1, ...]
        c[tid] = ((const float2*)contour)[tid];
    }
    __syncthreads();

    // Block handles 128 pixels; threads 0-127 do segments [0,64),
    // threads 128-255 do segments [64,128) of the same 128 pixels.
    const int lpix  = tid & 127;           // local pixel id
    const int half  = tid >> 7;            // 0 or 1
    const int start = half * HALF;

    const int p = blockIdx.x * 128 + lpix; // global pixel
    const int i = p >> 9;                  // row  (first meshgrid coord)
    const int j = p & (SIZE - 1);          // col  (second meshgrid coord)

    const float mx = (float)i * (1.0f / SIZE);
    const float my = (float)j * (1.0f / SIZE);

    const float K    = 100000.0f;
    const float EPS  = 1e-5f;
    const float PI_F = 3.14159265358979f;

    // diff at segment start; norm^2 carried across iterations
    float ax  = c[start].x - mx;
    float ay  = c[start].y - my;
    float na2 = ax * ax + ay * ay;

    float acc = 0.0f;

    #pragma unroll 8
    for (int n = 0; n < HALF; ++n) {
        const int n1 = (start + n + 1) & (NPTS - 1);
        const float2 cn = c[n1];           // wave-uniform -> LDS broadcast
        const float bx  = cn.x - mx;
        const float by  = cn.y - my;
        const float nb2 = bx * bx + by * by;

        // prod[...,1] - prod[...,0] = diff.y*roll.x - diff.x*roll.y
        const float cross = ay * bx - ax * by;
        const float dot   = ax * bx + ay * by;

        const float inv = __builtin_amdgcn_rsqf(na2 * nb2);  // v_rsq_f32
        float cosang = dot * inv;
        cosang = fminf(fmaxf(cosang, -1.0f + EPS), 1.0f - EPS);

        // acos via A&S 4.4.45: acos(x) = sqrt(1-x)*poly(x), x in [0,1];
        // acos(-x) = pi - acos(x). |err| <= 6.7e-5 rad.
        const float xa = fabsf(cosang);
        const float t  = __builtin_amdgcn_sqrtf(1.0f - xa);
        float poly = fmaf(-0.0187293f, xa, 0.0742610f);
        poly = fmaf(poly, xa, -0.2121144f);
        poly = fmaf(poly, xa, 1.5707288f);
        const float r0  = t * poly;
        const float ang = (cosang >= 0.0f) ? r0 : (PI_F - r0);

        // tanh(Kx) = 1 - 2/(exp(2Kx)+1), branchless, exact at saturation
        const float e = __expf(2.0f * K * cross);            // v_exp_f32
        const float s = fmaf(-2.0f, __builtin_amdgcn_rcpf(e + 1.0f), 1.0f);

        acc = fmaf(s, ang, acc);

        ax = bx; ay = by; na2 = nb2;
    }

    // Combine the two halves of each pixel's segment sum.
    if (half == 1) partial[lpix] = acc;
    __syncthreads();
    if (half == 0) {
        float r = (acc + partial[lpix]) * (1.0f / (2.0f * PI_F));
        r = fminf(fmaxf(r, 0.0f), 1.0f);
        out[p] = r;
    }
}

extern "C" void kernel_launch(void* const* d_in, const int* in_sizes, int n_in,
                              void* d_out, int out_size, void* d_ws, size_t ws_size,
                              hipStream_t stream) {
    const float* contour = (const float*)d_in[0];
    float* out = (float*)d_out;

    const int total = SIZE * SIZE;           // 262144 pixels
    const int block = 256;                   // 128 pixels x 2 halves
    const int grid  = total / 128;           // 2048 blocks

    contour_mask_kernel<<<grid, block, 0, stream>>>(contour, out);
}

// Round 6
// 77.881 us; speedup vs baseline: 1.0401x; 1.0401x over previous
//
#include <hip/hip_runtime.h>
#include <math.h>

#define SIZE 512
#define NPTS 128

__global__ __launch_bounds__(256) void contour_mask_kernel(
    const float* __restrict__ contour, float* __restrict__ out)
{
    __shared__ float2 c[NPTS];

    const int tid = threadIdx.x;
    if (tid < NPTS) {
        // contour is (128, 2) row-major: [x0, y0, x1, y1, ...]
        c[tid] = ((const float2*)contour)[tid];
    }
    __syncthreads();

    const int p = blockIdx.x * 256 + tid;
    const int i = p >> 9;         // row  (first meshgrid coord)
    const int j = p & (SIZE - 1); // col  (second meshgrid coord)

    const float mx = (float)i * (1.0f / SIZE);
    const float my = (float)j * (1.0f / SIZE);

    const float K    = 100000.0f;
    const float EPS  = 1e-5f;
    const float PI_F = 3.14159265358979f;
    // |cross| >= CTHR  =>  |tanh(K*cross) - sign(cross)| <= 1-tanh(6) = 1.2e-5
    const float CTHR = 6e-5f;

    // diff at segment start; norm^2 carried across iterations
    float ax  = c[0].x - mx;
    float ay  = c[0].y - my;
    float na2 = ax * ax + ay * ay;

    float acc = 0.0f;

    #pragma unroll 8
    for (int n = 0; n < NPTS; ++n) {
        const int n1 = (n + 1) & (NPTS - 1);
        const float2 cn = c[n1];           // wave-uniform -> LDS broadcast
        const float bx  = cn.x - mx;
        const float by  = cn.y - my;
        const float nb2 = bx * bx + by * by;

        // prod[...,1] - prod[...,0] = diff.y*roll.x - diff.x*roll.y
        const float cross = ay * bx - ax * by;
        const float dot   = ax * bx + ay * by;

        const float inv = __builtin_amdgcn_rsqf(na2 * nb2);  // v_rsq_f32
        const float cosang =
            __builtin_amdgcn_fmed3f(dot * inv, -1.0f + EPS, 1.0f - EPS);

        // acos via A&S 4.4.45: acos(x) = sqrt(1-x)*poly(x), x in [0,1];
        // acos(-x) = pi - acos(x). |err| <= 6.7e-5 rad.
        const float xa = fabsf(cosang);
        const float t  = __builtin_amdgcn_sqrtf(1.0f - xa);
        float poly = fmaf(-0.0187293f, xa, 0.0742610f);
        poly = fmaf(poly, xa, -0.2121144f);
        poly = fmaf(poly, xa, 1.5707288f);
        const float r0  = t * poly;
        const float ang = (cosang >= 0.0f) ? r0 : (PI_F - r0);

        // tanh(K*cross): for |cross| >= CTHR it is sign(cross) to 1.2e-5.
        // Wave-uniform branch: slow exp path only if ANY lane is in the
        // thin transition band (~0.2% of wave-iterations).
        float s;
        if (__any(fabsf(cross) < CTHR)) {
            const float e = __expf(2.0f * K * cross);        // v_exp_f32
            s = fmaf(-2.0f, __builtin_amdgcn_rcpf(e + 1.0f), 1.0f);
        } else {
            s = copysignf(1.0f, cross);                      // and+or, no trans
        }

        acc = fmaf(s, ang, acc);

        ax = bx; ay = by; na2 = nb2;
    }

    float r = acc * (1.0f / (2.0f * PI_F));
    r = fminf(fmaxf(r, 0.0f), 1.0f);
    out[p] = r;
}

extern "C" void kernel_launch(void* const* d_in, const int* in_sizes, int n_in,
                              void* d_out, int out_size, void* d_ws, size_t ws_size,
                              hipStream_t stream) {
    const float* contour = (const float*)d_in[0];
    float* out = (float*)d_out;

    const int total = SIZE * SIZE;   // 262144
    const int block = 256;
    const int grid  = total / block; // 1024

    contour_mask_kernel<<<grid, block, 0, stream>>>(contour, out);
}